// Round 1
// baseline (7363.374 us; speedup 1.0000x reference)
//
#include <hip/hip_runtime.h>
#include <cstdint>
#include <cstddef>

#define BATCH 4096
#define DIM 64
#define HID 512
#define H3 1536
#define NPER 2048
#define KEV 25
#define DT_C 0.01f
#define LOG_SQRT_2PI_C 0.9189385332046727f

__device__ __forceinline__ float sigmoidf_(float x) { return 1.0f / (1.0f + expf(-x)); }

// C[i,j] = epilogue( sum_k A[i,k]*Bw[j,k] + bias[j] )
// A: [Mdim,Kdim] row-major, Bw: [Ndim,Kdim] row-major (weights, x @ W^T)
// MODE 0: tanh   MODE 1: C += DT*(acc+bias) (read-modify-write)
// MODE 2: relu   MODE 3: plain
template<int MODE>
__global__ __launch_bounds__(256) void gemm_nt(
    const float* __restrict__ A, const float* __restrict__ Bw,
    const float* __restrict__ bias, float* __restrict__ C,
    int Mdim, int Ndim, int Kdim)
{
    __shared__ float As[16][64];
    __shared__ float Bs[16][64];
    const int tid  = threadIdx.x;
    const int brow = blockIdx.y * 64;   // M
    const int bcol = blockIdx.x * 64;   // N
    const int ty = tid >> 4, tx = tid & 15;
    const int lr = tid >> 2;            // 0..63 (row within tile)
    const int lk = (tid & 3) << 2;      // 0,4,8,12 (k within tile)

    float acc[4][4] = {};
    const float* Aptr = A  + (size_t)(brow + lr) * Kdim + lk;
    const float* Bptr = Bw + (size_t)(bcol + lr) * Kdim + lk;

    for (int k0 = 0; k0 < Kdim; k0 += 16) {
        float4 av = *(const float4*)(Aptr + k0);
        float4 bv = *(const float4*)(Bptr + k0);
        __syncthreads();
        As[lk+0][lr] = av.x; As[lk+1][lr] = av.y;
        As[lk+2][lr] = av.z; As[lk+3][lr] = av.w;
        Bs[lk+0][lr] = bv.x; Bs[lk+1][lr] = bv.y;
        Bs[lk+2][lr] = bv.z; Bs[lk+3][lr] = bv.w;
        __syncthreads();
        #pragma unroll
        for (int kk = 0; kk < 16; ++kk) {
            float4 a4 = *(const float4*)&As[kk][ty << 2];
            float4 b4 = *(const float4*)&Bs[kk][tx << 2];
            float aa[4] = {a4.x, a4.y, a4.z, a4.w};
            float bb[4] = {b4.x, b4.y, b4.z, b4.w};
            #pragma unroll
            for (int i = 0; i < 4; ++i)
                #pragma unroll
                for (int j = 0; j < 4; ++j)
                    acc[i][j] = fmaf(aa[i], bb[j], acc[i][j]);
        }
    }

    #pragma unroll
    for (int i = 0; i < 4; ++i) {
        int r = brow + (ty << 2) + i;
        #pragma unroll
        for (int j = 0; j < 4; ++j) {
            int c = bcol + (tx << 2) + j;
            float v = acc[i][j] + bias[c];
            size_t o = (size_t)r * Ndim + c;
            if (MODE == 0)      v = tanhf(v);
            else if (MODE == 1) v = C[o] + DT_C * v;
            else if (MODE == 2) v = fmaxf(v, 0.0f);
            C[o] = v;
        }
    }
}

// hg[i,:] = h[idx[i],:]   (i in [0,NPER))
__global__ __launch_bounds__(256) void gather_kernel(
    const float* __restrict__ h, const int* __restrict__ idx,
    float* __restrict__ hg)
{
    int t = blockIdx.x * 256 + threadIdx.x;   // over NPER*HID
    int i = t >> 9, j = t & 511;
    hg[t] = h[(size_t)idx[i] * HID + j];
}

__device__ __forceinline__ void block_atomic_sum(float v, float* acc) {
    __shared__ float red[4];
    #pragma unroll
    for (int off = 32; off > 0; off >>= 1) v += __shfl_down(v, off);
    int lane = threadIdx.x & 63, wid = threadIdx.x >> 6;
    if (lane == 0) red[wid] = v;
    __syncthreads();
    if (threadIdx.x == 0) atomicAdd(acc, red[0] + red[1] + red[2] + red[3]);
}

// p: [NPER, 2*DIM]  (mean | logvar); Xo,Mo: [NPER, DIM]
__global__ __launch_bounds__(256) void loss_kernel(
    const float* __restrict__ p, const float* __restrict__ Xo,
    const float* __restrict__ Mo, float* __restrict__ loss_acc)
{
    int t = blockIdx.x * 256 + threadIdx.x;   // over NPER*DIM
    int i = t >> 6, j = t & 63;
    float mean   = p[i * 128 + j];
    float logvar = p[i * 128 + 64 + j];
    float xo = Xo[t];
    float mo = Mo[t];
    float err = (xo - mean) * expf(-0.5f * logvar);
    float l = 0.5f * (err * err + logvar + 2.0f * LOG_SQRT_2PI_C) * mo;
    block_atomic_sum(l, loss_acc);
}

// GRU gate math + scatter: h[idx[i],j] = (1-z)*n + z*hg[i,j]
__global__ __launch_bounds__(256) void gru_scatter_kernel(
    const float* __restrict__ gi, const float* __restrict__ gh,
    const float* __restrict__ hg, const int* __restrict__ idx,
    float* __restrict__ h)
{
    int t = blockIdx.x * 256 + threadIdx.x;   // over NPER*HID
    int i = t >> 9, j = t & 511;
    size_t base = (size_t)i * H3;
    float ir = gi[base + j],           hr = gh[base + j];
    float iz = gi[base + HID + j],     hz = gh[base + HID + j];
    float in_ = gi[base + 2*HID + j],  hn = gh[base + 2*HID + j];
    float r = sigmoidf_(ir + hr);
    float z = sigmoidf_(iz + hz);
    float n = tanhf(in_ + r * hn);
    h[(size_t)idx[i] * HID + j] = (1.0f - z) * n + z * hg[t];
}

__global__ __launch_bounds__(256) void msum_kernel(
    const float* __restrict__ M, int n, float* __restrict__ m_acc)
{
    float v = 0.0f;
    for (int t = blockIdx.x * 256 + threadIdx.x; t < n; t += gridDim.x * 256)
        v += M[t];
    block_atomic_sum(v, m_acc);
}

__global__ void finalize_kernel(const float* __restrict__ sums, float* __restrict__ out) {
    if (threadIdx.x == 0) {
        out[0] = sums[0] / sums[1];
        out[1] = 0.0f;
    }
}

extern "C" void kernel_launch(void* const* d_in, const int* in_sizes, int n_in,
                              void* d_out, int out_size, void* d_ws, size_t ws_size,
                              hipStream_t stream) {
    const float* X        = (const float*)d_in[3];
    const float* M        = (const float*)d_in[4];
    const int*   batch_idx= (const int*)  d_in[5];
    const float* W_ode1   = (const float*)d_in[6];
    const float* b_ode1   = (const float*)d_in[7];
    const float* W_ode2   = (const float*)d_in[8];
    const float* b_ode2   = (const float*)d_in[9];
    const float* W_ih     = (const float*)d_in[10];
    const float* W_hh     = (const float*)d_in[11];
    const float* b_ih     = (const float*)d_in[12];
    const float* b_hh     = (const float*)d_in[13];
    const float* Wp1      = (const float*)d_in[14];
    const float* bp1      = (const float*)d_in[15];
    const float* Wp2      = (const float*)d_in[16];
    const float* bp2      = (const float*)d_in[17];
    float* out = (float*)d_out;

    // workspace layout (floats)
    float* ws = (float*)d_ws;
    float* h    = ws;                 // BATCH*HID          = 2,097,152
    float* tbuf = h    + (size_t)BATCH * HID;   // BATCH*HID
    float* hg   = tbuf + (size_t)BATCH * HID;   // NPER*HID  = 1,048,576
    float* q    = hg   + (size_t)NPER * HID;    // NPER*HID
    float* p    = q    + (size_t)NPER * HID;    // NPER*128  =   262,144
    float* gi   = p    + (size_t)NPER * 128;    // NPER*H3   = 3,145,728
    float* gh   = gi   + (size_t)NPER * H3;     // NPER*H3
    float* sums = gh   + (size_t)NPER * H3;     // [0]=loss, [1]=m_tot

    hipMemsetAsync(h,    0, (size_t)BATCH * HID * sizeof(float), stream);
    hipMemsetAsync(sums, 0, 2 * sizeof(float), stream);

    // m_tot (independent of the event loop)
    msum_kernel<<<1024, 256, 0, stream>>>(M, KEV * NPER * DIM, sums + 1);

    dim3 blk(256);
    dim3 gOde(HID / 64,  BATCH / 64);   // (8, 64)
    dim3 gQ  (HID / 64,  NPER / 64);    // (8, 32)
    dim3 gP  (128 / 64,  NPER / 64);    // (2, 32)
    dim3 gG  (H3 / 64,   NPER / 64);    // (24, 32)

    for (int k = 0; k < KEV; ++k) {
        const float* Xk = X + (size_t)k * NPER * DIM;
        const float* Mk = M + (size_t)k * NPER * DIM;
        const int* idxk = batch_idx + (size_t)k * NPER;

        // 2 Euler steps: h += DT * ( tanh(h W1^T + b1) W2^T + b2 )
        for (int s = 0; s < 2; ++s) {
            gemm_nt<0><<<gOde, blk, 0, stream>>>(h,    W_ode1, b_ode1, tbuf, BATCH, HID, HID);
            gemm_nt<1><<<gOde, blk, 0, stream>>>(tbuf, W_ode2, b_ode2, h,    BATCH, HID, HID);
        }

        // gather observed rows
        gather_kernel<<<NPER * HID / 256, blk, 0, stream>>>(h, idxk, hg);

        // head on observed rows only: q = relu(hg Wp1^T + bp1); p = q Wp2^T + bp2
        gemm_nt<2><<<gQ, blk, 0, stream>>>(hg, Wp1, bp1, q, NPER, HID, HID);
        gemm_nt<3><<<gP, blk, 0, stream>>>(q,  Wp2, bp2, p, NPER, 128, HID);
        loss_kernel<<<NPER * DIM / 256, blk, 0, stream>>>(p, Xk, Mk, sums);

        // GRU: gi = Xk W_ih^T + b_ih ; gh = hg W_hh^T + b_hh ; scatter update
        gemm_nt<3><<<gG, blk, 0, stream>>>(Xk, W_ih, b_ih, gi, NPER, H3, DIM);
        gemm_nt<3><<<gG, blk, 0, stream>>>(hg, W_hh, b_hh, gh, NPER, H3, HID);
        gru_scatter_kernel<<<NPER * HID / 256, blk, 0, stream>>>(gi, gh, hg, idxk, h);
    }

    finalize_kernel<<<1, 64, 0, stream>>>(sums, out);
}

// Round 2
// 2423.337 us; speedup vs baseline: 3.0385x; 3.0385x over previous
//
#include <hip/hip_runtime.h>
#include <cstdint>
#include <cstddef>

#define BATCH 4096
#define DIM 64
#define HID 512
#define H3 1536
#define NPER 2048
#define KEV 25
#define DT_C 0.01f
#define LOG_SQRT_2PI_C 0.9189385332046727f

typedef __attribute__((ext_vector_type(8))) short short8;
typedef __attribute__((ext_vector_type(4))) float f32x4;

__device__ __forceinline__ ushort f2bf(float f) {
    uint32_t u = __float_as_uint(f);
    u += 0x7FFF + ((u >> 16) & 1);      // round-to-nearest-even
    return (ushort)(u >> 16);
}
__device__ __forceinline__ float sigmoidf_(float x) { return 1.0f / (1.0f + expf(-x)); }

__device__ __forceinline__ void gload_lds16(const ushort* g, ushort* l) {
    __builtin_amdgcn_global_load_lds(
        (const __attribute__((address_space(1))) void*)g,
        (__attribute__((address_space(3))) void*)l, 16, 0, 0);
}

// C = epilogue(A @ Bw^T + bias). A:[M,K] bf16, Bw:[N,K] bf16, M,N,K % 64 == 0.
// MODE 0: Cb = bf16(tanh(v))
// MODE 1: C = C + DT*v (fp32), Cb = bf16(C)      (h update)
// MODE 2: Cb = bf16(relu(v))
// MODE 3: C = v (fp32)
template<int MODE>
__global__ __launch_bounds__(256) void mfma_gemm(
    const ushort* __restrict__ A, const ushort* __restrict__ Bw,
    const float* __restrict__ bias, float* __restrict__ C,
    ushort* __restrict__ Cb, int Mdim, int Ndim, int Kdim)
{
    __shared__ __align__(16) ushort Alds[64 * 64];
    __shared__ __align__(16) ushort Blds[64 * 64];
    const int tid  = threadIdx.x;
    const int lane = tid & 63;
    const int w    = tid >> 6;          // wave 0..3
    const int wr   = w >> 1, wc = w & 1;
    const int r0t  = blockIdx.y * 64;
    const int c0t  = blockIdx.x * 64;

    f32x4 acc[2][2] = {};
    const int sslot = lane & 7;

    for (int k0 = 0; k0 < Kdim; k0 += 64) {
        __syncthreads();   // previous tile's reads complete before overwrite
        #pragma unroll
        for (int cc = 0; cc < 2; ++cc) {
            const int row = w * 16 + 8 * cc + (lane >> 3);     // per-lane source row
            const int sg  = ((sslot ^ (row & 7)) << 3);        // pre-swizzled k-slot
            // LDS dest is wave-uniform; HW scatters lane*16B (linear)
            gload_lds16(A  + (size_t)(r0t + row) * Kdim + k0 + sg, &Alds[(w * 16 + 8 * cc) * 64]);
            gload_lds16(Bw + (size_t)(c0t + row) * Kdim + k0 + sg, &Blds[(w * 16 + 8 * cc) * 64]);
        }
        __syncthreads();   // drains vmcnt before barrier (compiler-inserted)

        short8 af[2][2], bfr[2][2];
        #pragma unroll
        for (int mi = 0; mi < 2; ++mi) {
            const int row = wr * 32 + mi * 16 + (lane & 15);
            #pragma unroll
            for (int ks = 0; ks < 2; ++ks) {
                const int slot = (ks * 4 + (lane >> 4)) ^ (row & 7);
                af[mi][ks] = *(const short8*)&Alds[row * 64 + slot * 8];
            }
        }
        #pragma unroll
        for (int ni = 0; ni < 2; ++ni) {
            const int col = wc * 32 + ni * 16 + (lane & 15);
            #pragma unroll
            for (int ks = 0; ks < 2; ++ks) {
                const int slot = (ks * 4 + (lane >> 4)) ^ (col & 7);
                bfr[ni][ks] = *(const short8*)&Blds[col * 64 + slot * 8];
            }
        }
        #pragma unroll
        for (int ks = 0; ks < 2; ++ks)
            #pragma unroll
            for (int mi = 0; mi < 2; ++mi)
                #pragma unroll
                for (int ni = 0; ni < 2; ++ni)
                    acc[mi][ni] = __builtin_amdgcn_mfma_f32_16x16x32_bf16(
                        af[mi][ks], bfr[ni][ks], acc[mi][ni], 0, 0, 0);
    }

    #pragma unroll
    for (int mi = 0; mi < 2; ++mi) {
        #pragma unroll
        for (int ni = 0; ni < 2; ++ni) {
            const int col = c0t + wc * 32 + ni * 16 + (lane & 15);
            const float bv = bias[col];
            #pragma unroll
            for (int i = 0; i < 4; ++i) {
                const int rowg = r0t + wr * 32 + mi * 16 + ((lane >> 4) << 2) + i;
                const size_t o = (size_t)rowg * Ndim + col;
                float v = acc[mi][ni][i] + bv;
                if (MODE == 0) {
                    Cb[o] = f2bf(tanhf(v));
                } else if (MODE == 1) {
                    float nh = C[o] + DT_C * v;
                    C[o] = nh; Cb[o] = f2bf(nh);
                } else if (MODE == 2) {
                    Cb[o] = f2bf(fmaxf(v, 0.0f));
                } else {
                    C[o] = v;
                }
            }
        }
    }
}

__global__ __launch_bounds__(256) void f2b4_kernel(
    const float* __restrict__ s, ushort* __restrict__ d, int n4)
{
    int t = blockIdx.x * 256 + threadIdx.x;
    if (t >= n4) return;
    float4 v = ((const float4*)s)[t];
    ushort4 o; o.x = f2bf(v.x); o.y = f2bf(v.y); o.z = f2bf(v.z); o.w = f2bf(v.w);
    ((ushort4*)d)[t] = o;
}

// hg[i,:] = h[idx[i],:]  (fp32 + bf16 shadow), vectorized x4
__global__ __launch_bounds__(256) void gather_kernel(
    const float* __restrict__ h, const int* __restrict__ idx,
    float* __restrict__ hg, ushort* __restrict__ hgb)
{
    int t = blockIdx.x * 256 + threadIdx.x;   // over NPER*HID/4
    int i = t >> 7, j4 = (t & 127) << 2;
    float4 v = *(const float4*)&h[(size_t)idx[i] * HID + j4];
    *(float4*)&hg[(size_t)t << 2] = v;
    ushort4 o; o.x = f2bf(v.x); o.y = f2bf(v.y); o.z = f2bf(v.z); o.w = f2bf(v.w);
    *(ushort4*)&hgb[(size_t)t << 2] = o;
}

__device__ __forceinline__ void block_atomic_sum(float v, float* acc) {
    __shared__ float red[4];
    #pragma unroll
    for (int off = 32; off > 0; off >>= 1) v += __shfl_down(v, off);
    int lane = threadIdx.x & 63, wid = threadIdx.x >> 6;
    if (lane == 0) red[wid] = v;
    __syncthreads();
    if (threadIdx.x == 0) atomicAdd(acc, red[0] + red[1] + red[2] + red[3]);
}

__global__ __launch_bounds__(256) void loss_kernel(
    const float* __restrict__ p, const float* __restrict__ Xo,
    const float* __restrict__ Mo, float* __restrict__ loss_acc)
{
    int t = blockIdx.x * 256 + threadIdx.x;   // over NPER*DIM
    int i = t >> 6, j = t & 63;
    float mean   = p[i * 128 + j];
    float logvar = p[i * 128 + 64 + j];
    float err = (Xo[t] - mean) * expf(-0.5f * logvar);
    float l = 0.5f * (err * err + logvar + 2.0f * LOG_SQRT_2PI_C) * Mo[t];
    block_atomic_sum(l, loss_acc);
}

__global__ __launch_bounds__(256) void gru_scatter_kernel(
    const float* __restrict__ gi, const float* __restrict__ gh,
    const float* __restrict__ hg, const int* __restrict__ idx,
    float* __restrict__ h, ushort* __restrict__ hb)
{
    int t = blockIdx.x * 256 + threadIdx.x;   // over NPER*HID/4
    int i = t >> 7, j4 = (t & 127) << 2;
    size_t base = (size_t)i * H3 + j4;
    float4 ir  = *(const float4*)&gi[base];
    float4 iz  = *(const float4*)&gi[base + HID];
    float4 in_ = *(const float4*)&gi[base + 2 * HID];
    float4 hr  = *(const float4*)&gh[base];
    float4 hz  = *(const float4*)&gh[base + HID];
    float4 hn  = *(const float4*)&gh[base + 2 * HID];
    float4 hgv = *(const float4*)&hg[(size_t)t << 2];
    float4 outv; ushort4 ob;
    #define GRU1(c) { float r = sigmoidf_(ir.c + hr.c); float z = sigmoidf_(iz.c + hz.c); \
        float n = tanhf(in_.c + r * hn.c); float nh = (1.0f - z) * n + z * hgv.c; \
        outv.c = nh; ob.c = f2bf(nh); }
    GRU1(x) GRU1(y) GRU1(z) GRU1(w)
    #undef GRU1
    size_t ro = (size_t)idx[i] * HID + j4;
    *(float4*)&h[ro]  = outv;
    *(ushort4*)&hb[ro] = ob;
}

__global__ __launch_bounds__(256) void msum_kernel(
    const float* __restrict__ M, int n, float* __restrict__ m_acc)
{
    float v = 0.0f;
    for (int t = blockIdx.x * 256 + threadIdx.x; t < n; t += gridDim.x * 256)
        v += M[t];
    block_atomic_sum(v, m_acc);
}

__global__ void finalize_kernel(const float* __restrict__ sums, float* __restrict__ out) {
    if (threadIdx.x == 0) { out[0] = sums[0] / sums[1]; out[1] = 0.0f; }
}

extern "C" void kernel_launch(void* const* d_in, const int* in_sizes, int n_in,
                              void* d_out, int out_size, void* d_ws, size_t ws_size,
                              hipStream_t stream) {
    const float* X      = (const float*)d_in[3];
    const float* M      = (const float*)d_in[4];
    const int* batch_idx= (const int*)  d_in[5];
    const float* W_ode1 = (const float*)d_in[6];
    const float* b_ode1 = (const float*)d_in[7];
    const float* W_ode2 = (const float*)d_in[8];
    const float* b_ode2 = (const float*)d_in[9];
    const float* W_ih   = (const float*)d_in[10];
    const float* W_hh   = (const float*)d_in[11];
    const float* b_ih   = (const float*)d_in[12];
    const float* b_hh   = (const float*)d_in[13];
    const float* Wp1    = (const float*)d_in[14];
    const float* bp1    = (const float*)d_in[15];
    const float* Wp2    = (const float*)d_in[16];
    const float* bp2    = (const float*)d_in[17];
    float* out = (float*)d_out;

    // ---- workspace layout ----
    float* ws   = (float*)d_ws;
    float* h    = ws;                                   // 4096*512
    float* hg   = h   + (size_t)BATCH * HID;            // 2048*512
    float* pbuf = hg  + (size_t)NPER * HID;             // 2048*128
    float* gi   = pbuf+ (size_t)NPER * 128;             // 2048*1536
    float* gh   = gi  + (size_t)NPER * H3;              // 2048*1536
    float* sums = gh  + (size_t)NPER * H3;              // 16 (pad)
    ushort* hb   = (ushort*)(sums + 16);                // 4096*512
    ushort* tbb  = hb   + (size_t)BATCH * HID;          // 4096*512
    ushort* hgb  = tbb  + (size_t)BATCH * HID;          // 2048*512
    ushort* qb   = hgb  + (size_t)NPER * HID;           // 2048*512
    ushort* Xb   = qb   + (size_t)NPER * HID;           // 25*2048*64
    ushort* W1b  = Xb   + (size_t)KEV * NPER * DIM;     // 512*512
    ushort* W2b  = W1b  + (size_t)HID * HID;
    ushort* Wp1b = W2b  + (size_t)HID * HID;            // 512*512
    ushort* Wp2b = Wp1b + (size_t)HID * HID;            // 128*512
    ushort* Wihb = Wp2b + (size_t)2 * DIM * HID;        // 1536*64
    ushort* Whhb = Wihb + (size_t)H3 * DIM;             // 1536*512

    hipMemsetAsync(h,    0, (size_t)BATCH * HID * sizeof(float), stream);
    hipMemsetAsync(hb,   0, (size_t)BATCH * HID * sizeof(ushort), stream);
    hipMemsetAsync(sums, 0, 2 * sizeof(float), stream);

    dim3 blk(256);
    // weight/X -> bf16 (once per call)
    auto cvt = [&](const float* s, ushort* d, size_t n) {
        f2b4_kernel<<<dim3((n / 4 + 255) / 256), blk, 0, stream>>>(s, d, (int)(n / 4));
    };
    cvt(W_ode1, W1b,  (size_t)HID * HID);
    cvt(W_ode2, W2b,  (size_t)HID * HID);
    cvt(Wp1,    Wp1b, (size_t)HID * HID);
    cvt(Wp2,    Wp2b, (size_t)2 * DIM * HID);
    cvt(W_ih,   Wihb, (size_t)H3 * DIM);
    cvt(W_hh,   Whhb, (size_t)H3 * HID);
    cvt(X,      Xb,   (size_t)KEV * NPER * DIM);

    msum_kernel<<<1024, blk, 0, stream>>>(M, KEV * NPER * DIM, sums + 1);

    dim3 gOde(HID / 64, BATCH / 64);   // (8, 64)
    dim3 gQ  (HID / 64, NPER / 64);    // (8, 32)
    dim3 gP  (128 / 64, NPER / 64);    // (2, 32)
    dim3 gG  (H3  / 64, NPER / 64);    // (24, 32)

    for (int k = 0; k < KEV; ++k) {
        const float*  Xk  = X  + (size_t)k * NPER * DIM;
        const float*  Mk  = M  + (size_t)k * NPER * DIM;
        const ushort* Xbk = Xb + (size_t)k * NPER * DIM;
        const int*   idxk = batch_idx + (size_t)k * NPER;

        for (int s = 0; s < 2; ++s) {
            mfma_gemm<0><<<gOde, blk, 0, stream>>>(hb,  W1b, b_ode1, nullptr, tbb, BATCH, HID, HID);
            mfma_gemm<1><<<gOde, blk, 0, stream>>>(tbb, W2b, b_ode2, h,       hb,  BATCH, HID, HID);
        }

        gather_kernel<<<NPER * HID / 4 / 256, blk, 0, stream>>>(h, idxk, hg, hgb);

        mfma_gemm<2><<<gQ, blk, 0, stream>>>(hgb, Wp1b, bp1, nullptr, qb, NPER, HID, HID);
        mfma_gemm<3><<<gP, blk, 0, stream>>>(qb,  Wp2b, bp2, pbuf, nullptr, NPER, 128, HID);
        loss_kernel<<<NPER * DIM / 256, blk, 0, stream>>>(pbuf, Xk, Mk, sums);

        mfma_gemm<3><<<gG, blk, 0, stream>>>(Xbk, Wihb, b_ih, gi, nullptr, NPER, H3, DIM);
        mfma_gemm<3><<<gG, blk, 0, stream>>>(hgb, Whhb, b_hh, gh, nullptr, NPER, H3, HID);
        gru_scatter_kernel<<<NPER * HID / 4 / 256, blk, 0, stream>>>(gi, gh, hg, idxk, h, hb);
    }

    finalize_kernel<<<1, 64, 0, stream>>>(sums, out);
}